// Round 2
// baseline (2702.411 us; speedup 1.0000x reference)
//
#include <hip/hip_runtime.h>
#include <cfloat>

// Problem constants (match reference)
constexpr int Bn = 1024, Ln = 1024, Vn = 20, Dn = 128;

// v mod 20 for 0 <= v <= ~1000 (magic multiply, exact in this range)
__device__ __forceinline__ int mod20(int v) { return v - 20 * ((v * 205) >> 12); }

__global__ __launch_bounds__(64, 1) void daf_chain(
    const float* __restrict__ x, const float* __restrict__ emb,
    const float* __restrict__ W, const float* __restrict__ bvec,
    float* __restrict__ out)
{
  __shared__ alignas(16) double state64[Dn];  // broadcast copy of state, f64
  __shared__ float  embs[Vn * Dn];            // emb rows, f32
  __shared__ unsigned char aidx[Ln];          // input token index per step

  const int lane  = threadIdx.x;
  const int batch = blockIdx.x;

  // Lanes 0..19 -> loc outputs j=0..19 (argmax over lanes 0..31),
  // lanes 32..51 -> scale outputs j=20..39 (argmax over lanes 32..63).
  const bool active = (lane < Vn) || (lane >= 32 && lane < 32 + Vn);
  const int  jm     = (lane < 32) ? lane : (lane - 32 + Vn);

  // Per-lane W column, f64, pinned into VGPRs (opaque to rematerialization).
  double wcol[Dn];
#pragma unroll
  for (int d = 0; d < Dn; ++d)
    wcol[d] = active ? (double)W[d * (2 * Vn) + jm] : 0.0;
#pragma unroll
  for (int d = 0; d < Dn; ++d)
    asm volatile("" : "+v"(wcol[d]));   // pin: forbid remat/sink of the W loads
  const double bj = active ? (double)bvec[jm] : 0.0;

  // Stage emb into LDS (coalesced)
  for (int i = lane; i < Vn * Dn; i += 64) embs[i] = emb[i];

  // Extract this batch's token indices from the one-hot x (coalesced reads)
  const float* xb = x + (size_t)batch * Ln * Vn;
  for (int i = lane; i < Ln * Vn; i += 64) {
    if (xb[i] > 0.5f) aidx[i / Vn] = (unsigned char)(i % Vn);
  }

  // f32 master state in registers (lane owns d=lane, d=lane+64); f64 copy in LDS.
  state64[lane]      = 0.0;
  state64[lane + 64] = 0.0;
  float s32a = 0.0f, s32b = 0.0f;

  __syncthreads();

  float* outb = out + (size_t)batch * Ln * Vn;
  const double2* st2 = (const double2*)state64;

  for (int t = 0; t < Ln; ++t) {
    const int a = (int)aidx[t];  // issued early; hidden under the dot

    // net_j = sum_d state[d] * W[d][j] in f64 (exact products, ~1e-16 sum error)
    double acc0 = 0.0, acc1 = 0.0, acc2 = 0.0, acc3 = 0.0;
#pragma unroll
    for (int i = 0; i < Dn / 2; i += 2) {
      const double2 sA = st2[i];      // uniform address -> LDS broadcast read
      const double2 sB = st2[i + 1];
      acc0 = __builtin_fma(sA.x, wcol[2 * i + 0], acc0);
      acc1 = __builtin_fma(sA.y, wcol[2 * i + 1], acc1);
      acc2 = __builtin_fma(sB.x, wcol[2 * i + 2], acc2);
      acc3 = __builtin_fma(sB.y, wcol[2 * i + 3], acc3);
    }
    const double net = ((acc0 + acc1) + (acc2 + acc3)) + bj;

    // Two width-32 argmax butterflies; tie-break smaller index (jnp.argmax).
    double v = active ? net : -DBL_MAX;
    int idx = jm;
#pragma unroll
    for (int off = 16; off >= 1; off >>= 1) {
      double ov = __shfl_xor(v, off);
      int    oi = __shfl_xor(idx, off);
      const bool take = (ov > v) || (ov == v && oi < idx);
      v   = take ? ov : v;
      idx = take ? oi : idx;
    }
    const int loc   = __shfl(idx, 0);        // 0..19
    const int scale = __shfl(idx, 32) - Vn;  // 0..19

    // out_idx = (inv20(scale) * ((a - loc) mod 20)) mod 20
    int r = a - loc; r += (r >> 31) & Vn;
    const int s  = scale;
    const int s2 = mod20(s * s);
    const int s4 = mod20(s2 * s2);
    const int s6 = mod20(s4 * s2);
    int inv = mod20(s6 * s);                 // s^7 mod 20 (= s^-1 for coprime s)
    const bool cop = ((s & 1) != 0) && ((s - 5 * ((s * 205) >> 10)) != 0);
    inv = cop ? inv : 0;                     // non-coprime -> INV_P row = e_0
    const int oidx = mod20(inv * r);

    // One-hot output row (80B wave store, fire-and-forget)
    if (lane < Vn) outb[(size_t)t * Vn + lane] = (lane == oidx) ? 1.0f : 0.0f;

    // Exact fp32 state walk (bit-reproducible), then refresh f64 LDS copy.
    {
      const float e0 = embs[oidx * Dn + lane];
      const float e1 = embs[oidx * Dn + lane + 64];
      s32a += e0;
      s32b += e1;
      state64[lane]      = (double)s32a;
      state64[lane + 64] = (double)s32b;
    }
    __syncthreads();  // 1 wave: cheap; orders state64 writes before next reads
  }
}

extern "C" void kernel_launch(void* const* d_in, const int* in_sizes, int n_in,
                              void* d_out, int out_size, void* d_ws, size_t ws_size,
                              hipStream_t stream) {
  const float* x   = (const float*)d_in[0];
  const float* emb = (const float*)d_in[1];
  const float* W   = (const float*)d_in[2];
  const float* b   = (const float*)d_in[3];
  float* out = (float*)d_out;
  hipLaunchKernelGGL(daf_chain, dim3(Bn), dim3(64), 0, stream,
                     x, emb, W, b, out);
}

// Round 3
// 2702.233 us; speedup vs baseline: 1.0001x; 1.0001x over previous
//
#include <hip/hip_runtime.h>
#include <cfloat>

// Problem constants (match reference)
constexpr int Bn = 1024, Ln = 1024, Vn = 20, Dn = 128;

// v mod 20 for 0 <= v <= ~1000 (magic multiply, exact in this range)
__device__ __forceinline__ int mod20(int v) { return v - 20 * ((v * 205) >> 12); }

// ---- X-macro machinery: 128 NAMED double scalars so no alloca/scratch ----
// Declare + load: w<i> = (double)Wcol[i*40]
#define W8(a,b,c,d,e,f,g,h) \
  double w##a = (double)Wcol[(a)*40]; double w##b = (double)Wcol[(b)*40]; \
  double w##c = (double)Wcol[(c)*40]; double w##d = (double)Wcol[(d)*40]; \
  double w##e = (double)Wcol[(e)*40]; double w##f = (double)Wcol[(f)*40]; \
  double w##g = (double)Wcol[(g)*40]; double w##h = (double)Wcol[(h)*40];

// Dot-product steps: two doubles per LDS b128 read, 4 accumulator chains
#define DA(i,j) { const double2 s_ = st2[(i)>>1]; \
  acc0 = __builtin_fma(s_.x, w##i, acc0); acc1 = __builtin_fma(s_.y, w##j, acc1); }
#define DB(i,j) { const double2 s_ = st2[(i)>>1]; \
  acc2 = __builtin_fma(s_.x, w##i, acc2); acc3 = __builtin_fma(s_.y, w##j, acc3); }
#define G8(a,b,c,d,e,f,g,h) DA(a,b) DB(c,d) DA(e,f) DB(g,h)

__global__ __launch_bounds__(64, 1) void daf_chain(
    const float* __restrict__ x, const float* __restrict__ emb,
    const float* __restrict__ W, const float* __restrict__ bvec,
    float* __restrict__ out)
{
  __shared__ alignas(16) double state64[Dn];  // broadcast copy of state, f64
  __shared__ float  embs[Vn * Dn];            // emb rows, f32
  __shared__ unsigned char aidx[Ln];          // input token index per step

  const int lane  = threadIdx.x;
  const int batch = blockIdx.x;

  // Lanes 0..19 -> loc outputs j=0..19 (argmax over lanes 0..31),
  // lanes 32..51 -> scale outputs j=20..39 (argmax over lanes 32..63).
  const bool active = (lane < Vn) || (lane >= 32 && lane < 32 + Vn);
  const int  jm     = (lane < 32) ? lane : (lane - 32 + Vn);
  const int  jc     = active ? jm : 0;        // clamp idle lanes in-bounds

  // 128 named f64 scalars holding this lane's W column (SSA -> VGPRs).
  const float* Wcol = W + jc;
  W8(0,1,2,3,4,5,6,7)          W8(8,9,10,11,12,13,14,15)
  W8(16,17,18,19,20,21,22,23)  W8(24,25,26,27,28,29,30,31)
  W8(32,33,34,35,36,37,38,39)  W8(40,41,42,43,44,45,46,47)
  W8(48,49,50,51,52,53,54,55)  W8(56,57,58,59,60,61,62,63)
  W8(64,65,66,67,68,69,70,71)  W8(72,73,74,75,76,77,78,79)
  W8(80,81,82,83,84,85,86,87)  W8(88,89,90,91,92,93,94,95)
  W8(96,97,98,99,100,101,102,103)     W8(104,105,106,107,108,109,110,111)
  W8(112,113,114,115,116,117,118,119) W8(120,121,122,123,124,125,126,127)
  const double bj = (double)bvec[jc];

  // Stage emb into LDS (coalesced)
  for (int i = lane; i < Vn * Dn; i += 64) embs[i] = emb[i];

  // Extract this batch's token indices from the one-hot x (coalesced reads)
  const float* xb = x + (size_t)batch * Ln * Vn;
  for (int i = lane; i < Ln * Vn; i += 64) {
    if (xb[i] > 0.5f) aidx[i / Vn] = (unsigned char)(i % Vn);
  }

  // f32 master state in registers (lane owns d=lane, d=lane+64); f64 copy in LDS.
  state64[lane]      = 0.0;
  state64[lane + 64] = 0.0;
  float s32a = 0.0f, s32b = 0.0f;

  __syncthreads();

  float* outb = out + (size_t)batch * Ln * Vn;
  const double2* st2 = (const double2*)state64;

  for (int t = 0; t < Ln; ++t) {
    const int a = (int)aidx[t];  // issued early; hidden under the dot

    // net_j = sum_d state[d] * W[d][j] in f64 (exact products, ~1e-16 sum error)
    double acc0 = 0.0, acc1 = 0.0, acc2 = 0.0, acc3 = 0.0;
    G8(0,1,2,3,4,5,6,7)          G8(8,9,10,11,12,13,14,15)
    G8(16,17,18,19,20,21,22,23)  G8(24,25,26,27,28,29,30,31)
    G8(32,33,34,35,36,37,38,39)  G8(40,41,42,43,44,45,46,47)
    G8(48,49,50,51,52,53,54,55)  G8(56,57,58,59,60,61,62,63)
    G8(64,65,66,67,68,69,70,71)  G8(72,73,74,75,76,77,78,79)
    G8(80,81,82,83,84,85,86,87)  G8(88,89,90,91,92,93,94,95)
    G8(96,97,98,99,100,101,102,103)     G8(104,105,106,107,108,109,110,111)
    G8(112,113,114,115,116,117,118,119) G8(120,121,122,123,124,125,126,127)
    const double net = ((acc0 + acc1) + (acc2 + acc3)) + bj;

    // Two width-32 argmax butterflies; tie-break smaller index (jnp.argmax).
    double v = active ? net : -DBL_MAX;
    int idx = jm;
#pragma unroll
    for (int off = 16; off >= 1; off >>= 1) {
      double ov = __shfl_xor(v, off);
      int    oi = __shfl_xor(idx, off);
      const bool take = (ov > v) || (ov == v && oi < idx);
      v   = take ? ov : v;
      idx = take ? oi : idx;
    }
    const int loc   = __shfl(idx, 0);        // 0..19
    const int scale = __shfl(idx, 32) - Vn;  // 0..19

    // out_idx = (inv20(scale) * ((a - loc) mod 20)) mod 20
    int r = a - loc; r += (r >> 31) & Vn;
    const int s  = scale;
    const int s2 = mod20(s * s);
    const int s4 = mod20(s2 * s2);
    const int s6 = mod20(s4 * s2);
    int inv = mod20(s6 * s);                 // s^7 mod 20 (= s^-1 for coprime s)
    const bool cop = ((s & 1) != 0) && ((s - 5 * ((s * 205) >> 10)) != 0);
    inv = cop ? inv : 0;                     // non-coprime -> INV_P row = e_0
    const int oidx = mod20(inv * r);

    // One-hot output row (80B wave store, fire-and-forget)
    if (lane < Vn) outb[(size_t)t * Vn + lane] = (lane == oidx) ? 1.0f : 0.0f;

    // Exact fp32 state walk (bit-reproducible), then refresh f64 LDS copy.
    {
      const float e0 = embs[oidx * Dn + lane];
      const float e1 = embs[oidx * Dn + lane + 64];
      s32a += e0;
      s32b += e1;
      state64[lane]      = (double)s32a;
      state64[lane + 64] = (double)s32b;
    }
    __syncthreads();  // 1 wave: cheap; orders state64 writes before next reads
  }
}

extern "C" void kernel_launch(void* const* d_in, const int* in_sizes, int n_in,
                              void* d_out, int out_size, void* d_ws, size_t ws_size,
                              hipStream_t stream) {
  const float* x   = (const float*)d_in[0];
  const float* emb = (const float*)d_in[1];
  const float* W   = (const float*)d_in[2];
  const float* b   = (const float*)d_in[3];
  float* out = (float*)d_out;
  hipLaunchKernelGGL(daf_chain, dim3(Bn), dim3(64), 0, stream,
                     x, emb, W, b, out);
}

// Round 4
// 934.531 us; speedup vs baseline: 2.8917x; 2.8915x over previous
//
#include <hip/hip_runtime.h>
#include <cfloat>

// Problem constants (match reference)
constexpr int Bn = 1024, Ln = 1024, Vn = 20, Dn = 128;
constexpr int NJ = 2 * Vn;      // 40 output columns
constexpr int RESYNC = 16;      // full f64 dot every RESYNC steps

// v mod 20 for 0 <= v <= ~1000 (magic multiply, exact in this range)
__device__ __forceinline__ int mod20(int v) { return v - 20 * ((v * 205) >> 12); }

__global__ __launch_bounds__(64, 1) void daf_chain(
    const float* __restrict__ x, const float* __restrict__ emb,
    const float* __restrict__ W, const float* __restrict__ bvec,
    float* __restrict__ out)
{
  __shared__ float  Ws[Dn * NJ];              // 20480 B: W staged f32
  __shared__ float  embs[Vn * Dn];            // 10240 B
  __shared__ double EW[Vn * NJ];              //  6400 B: EW[k][j] = emb[k]·W[:,j]
  __shared__ alignas(16) double st64[Dn];     //  1024 B: f64 copy of f32 state
  __shared__ unsigned char aidx[Ln];          //  1024 B: token index per step
  // total 39168 B -> 4 blocks/CU

  const int lane  = threadIdx.x;
  const int batch = blockIdx.x;

  // Lanes 0..19 -> loc outputs j=0..19 (argmax over lanes 0..31),
  // lanes 32..51 -> scale outputs j=20..39 (argmax over lanes 32..63).
  const bool active = (lane < Vn) || (lane >= 32 && lane < 32 + Vn);
  const int  jm     = (lane < 32) ? lane : (lane - 32 + Vn);
  const int  jc     = active ? jm : 0;        // clamp idle lanes in-bounds

  // ---- Prologue: stage W, emb; extract token indices (coalesced float4) ----
  for (int i = lane; i < Dn * NJ; i += 64) Ws[i] = W[i];
  for (int i = lane; i < Vn * Dn; i += 64) embs[i] = emb[i];
  const float4* xb4 = (const float4*)(x + (size_t)batch * Ln * Vn);
  for (int i = lane; i < Ln * (Vn / 4); i += 64) {  // 5 float4 per row of 20
    const float4 v = xb4[i];
    const int row = i / 5, cb = (i % 5) * 4;
    if (v.x > 0.5f) aidx[row] = (unsigned char)(cb + 0);
    if (v.y > 0.5f) aidx[row] = (unsigned char)(cb + 1);
    if (v.z > 0.5f) aidx[row] = (unsigned char)(cb + 2);
    if (v.w > 0.5f) aidx[row] = (unsigned char)(cb + 3);
  }
  __syncthreads();

  // ---- EW[k][j] = sum_d emb[k][d] * W[d][j], f64 (800 entries / 64 lanes) ----
  for (int p = lane; p < Vn * NJ; p += 64) {
    const int k = p / NJ, j = p - k * NJ;
    double acc = 0.0;
#pragma unroll 4
    for (int d = 0; d < Dn; ++d)
      acc = __builtin_fma((double)embs[k * Dn + d], (double)Ws[d * NJ + j], acc);
    EW[p] = acc;
  }
  __syncthreads();

  // Per-lane EW column: 20 named f64 scalars (register-resident, selected by tree)
  const double* EWc = EW + jc;
  const double e0 = EWc[0*NJ],  e1 = EWc[1*NJ],  e2 = EWc[2*NJ],  e3 = EWc[3*NJ];
  const double e4 = EWc[4*NJ],  e5 = EWc[5*NJ],  e6 = EWc[6*NJ],  e7 = EWc[7*NJ];
  const double e8 = EWc[8*NJ],  e9 = EWc[9*NJ],  e10 = EWc[10*NJ], e11 = EWc[11*NJ];
  const double e12 = EWc[12*NJ], e13 = EWc[13*NJ], e14 = EWc[14*NJ], e15 = EWc[15*NJ];
  const double e16 = EWc[16*NJ], e17 = EWc[17*NJ], e18 = EWc[18*NJ], e19 = EWc[19*NJ];

  const double bj = (double)bvec[jc];
  double net = bj;                 // net at t=0 is exactly b
  float s32a = 0.0f, s32b = 0.0f;  // bit-exact f32 state walk (lane, lane+64)
  st64[lane] = 0.0; st64[lane + 64] = 0.0;

  float* outb = out + (size_t)batch * Ln * Vn;
  const double2* st2 = (const double2*)st64;
  const float* Wsc = Ws + jc;

  for (int t = 0; t < Ln; ++t) {
    const int a = (int)aidx[t];    // issued early; hidden under argmax chain

    if ((t & (RESYNC - 1)) == 0 && t > 0) {
      // Resync: net = b + f64 dot of the exact f32 state (same math that
      // passed with absmax 0.0 in R1-R3, just amortized over 16 steps).
      double acc0 = 0.0, acc1 = 0.0, acc2 = 0.0, acc3 = 0.0;
#pragma unroll
      for (int d = 0; d < Dn; d += 4) {
        const double2 sA = st2[d >> 1];
        const double2 sB = st2[(d >> 1) + 1];
        acc0 = __builtin_fma(sA.x, (double)Wsc[(d + 0) * NJ], acc0);
        acc1 = __builtin_fma(sA.y, (double)Wsc[(d + 1) * NJ], acc1);
        acc2 = __builtin_fma(sB.x, (double)Wsc[(d + 2) * NJ], acc2);
        acc3 = __builtin_fma(sB.y, (double)Wsc[(d + 3) * NJ], acc3);
      }
      net = ((acc0 + acc1) + (acc2 + acc3)) + bj;
    }

    // Argmax butterflies on f32 keys; tie-break smaller index (jnp.argmax).
    float key = active ? (float)net : -FLT_MAX;
    int   idx = jm;
#pragma unroll
    for (int off = 16; off >= 1; off >>= 1) {
      const float ov = __shfl_xor(key, off);
      const int   oi = __shfl_xor(idx, off);
      const bool take = (ov > key) || (ov == key && oi < idx);
      key = take ? ov : key;
      idx = take ? oi : idx;
    }
    const int loc   = __shfl(idx, 0);        // 0..19
    const int scale = __shfl(idx, 32) - Vn;  // 0..19

    // out_idx = (inv20(scale) * ((a - loc) mod 20)) mod 20
    int r = a - loc; r += (r >> 31) & Vn;
    const int s  = scale;
    const int s2 = mod20(s * s);
    const int s4 = mod20(s2 * s2);
    const int s6 = mod20(s4 * s2);
    int inv = mod20(s6 * s);                 // s^7 mod 20 (= s^-1 for coprime s)
    const bool cop = ((s & 1) != 0) && ((s - 5 * ((s * 205) >> 10)) != 0);
    inv = cop ? inv : 0;                     // non-coprime -> INV_P row = e_0
    const int oidx = mod20(inv * r);

    // One-hot output row (80B wave store, fire-and-forget)
    if (lane < Vn) outb[(size_t)t * Vn + lane] = (lane == oidx) ? 1.0f : 0.0f;

    // Exact f32 state walk (bit-reproducible); refresh f64 LDS copy.
    s32a += embs[oidx * Dn + lane];
    s32b += embs[oidx * Dn + lane + 64];
    st64[lane]      = (double)s32a;
    st64[lane + 64] = (double)s32b;

    // Incremental net for next step: net += EW[oidx][j], 19-select cndmask tree.
    {
      const int b0 = oidx & 1, b1 = oidx & 2, b2 = oidx & 4, b3 = oidx & 8, b4 = oidx & 16;
      const double t0 = b0 ? e1  : e0,  t1 = b0 ? e3  : e2,  t2 = b0 ? e5  : e4;
      const double t3 = b0 ? e7  : e6,  t4 = b0 ? e9  : e8,  t5 = b0 ? e11 : e10;
      const double t6 = b0 ? e13 : e12, t7 = b0 ? e15 : e14, t8 = b0 ? e17 : e16;
      const double t9 = b0 ? e19 : e18;
      const double u0 = b1 ? t1 : t0, u1 = b1 ? t3 : t2, u2 = b1 ? t5 : t4;
      const double u3 = b1 ? t7 : t6, u4 = b1 ? t9 : t8;
      const double v0 = b2 ? u1 : u0, v1 = b2 ? u3 : u2;   // 16..19 have b2==0
      const double w0 = b3 ? v1 : v0;
      net += b4 ? u4 : w0;
    }
  }
}

extern "C" void kernel_launch(void* const* d_in, const int* in_sizes, int n_in,
                              void* d_out, int out_size, void* d_ws, size_t ws_size,
                              hipStream_t stream) {
  const float* x   = (const float*)d_in[0];
  const float* emb = (const float*)d_in[1];
  const float* W   = (const float*)d_in[2];
  const float* b   = (const float*)d_in[3];
  float* out = (float*)d_out;
  hipLaunchKernelGGL(daf_chain, dim3(Bn), dim3(64), 0, stream,
                     x, emb, W, b, out);
}